// Round 2
// baseline (591.054 us; speedup 1.0000x reference)
//
#include <hip/hip_runtime.h>

typedef __bf16 bf16;
typedef __bf16 bf16x8 __attribute__((ext_vector_type(8)));
typedef float f32x4 __attribute__((ext_vector_type(4)));

#define NIMG 16
#define CCH 256
#define HH 56
#define HP 58
#define NBLK (NIMG * HH)        // 896 conv blocks
#define NPOSV (NIMG * HH * HH)  // 50176 valid positions
#define WELEMS 589824           // 256*256*3*3

typedef const __attribute__((address_space(1))) void* gas1_t;
typedef __attribute__((address_space(3))) void* las3_t;

__device__ __forceinline__ void gload16(const void* g, void* l) {
  __builtin_amdgcn_global_load_lds((gas1_t)g, (las3_t)l, 16, 0, 0);
}

// ---------------- weight quantization ----------------

__global__ __launch_bounds__(256) void w_partial(const float* __restrict__ w1,
                                                 const float* __restrict__ w2,
                                                 double* __restrict__ psum,
                                                 float* __restrict__ pmn,
                                                 float* __restrict__ pmx) {
  int b = blockIdx.x;            // 256 blocks: 128 per weight
  int lb = b & 127;
  const float* w = (b >> 7) ? w2 : w1;
  int t = threadIdx.x;
  double s = 0.0;
  float mn = 3.4028235e38f, mx = -3.4028235e38f;
  for (int i = lb * 4608 + t; i < (lb + 1) * 4608; i += 256) {
    float v = w[i];
    s += (double)v;
    mn = fminf(mn, v);
    mx = fmaxf(mx, v);
  }
  __shared__ double sd[256];
  __shared__ float smn[256], smx[256];
  sd[t] = s; smn[t] = mn; smx[t] = mx;
  __syncthreads();
  for (int st = 128; st > 0; st >>= 1) {
    if (t < st) {
      sd[t] += sd[t + st];
      smn[t] = fminf(smn[t], smn[t + st]);
      smx[t] = fmaxf(smx[t], smx[t + st]);
    }
    __syncthreads();
  }
  if (t == 0) { psum[b] = sd[0]; pmn[b] = smn[0]; pmx[b] = smx[0]; }
}

__global__ void w_finalize(const double* __restrict__ psum,
                           const float* __restrict__ pmn,
                           const float* __restrict__ pmx,
                           float* __restrict__ wq) {
  int t = threadIdx.x;
  if (t < 2) {
    double s = 0.0;
    float mn = 3.4028235e38f, mx = -3.4028235e38f;
    for (int b = t * 128; b < (t + 1) * 128; b++) {
      s += psum[b];
      mn = fminf(mn, pmn[b]);
      mx = fmaxf(mx, pmx[b]);
    }
    float mean = (float)(s / (double)WELEMS);
    float tmn = mn - mean, tmx = mx - mean;
    float d = (tmx - tmn) / 3.0f;
    wq[t * 4 + 0] = mean;
    wq[t * 4 + 1] = tmn + d;   // lo
    wq[t * 4 + 2] = tmx - d;   // hi
  }
}

// produce B^T layout: bt[o][k], k = (kh*3+kw)*256 + c, center tap doubled
__global__ __launch_bounds__(256) void w_quant(const float* __restrict__ w1,
                                               const float* __restrict__ w2,
                                               const float* __restrict__ wq,
                                               bf16* __restrict__ bt1,
                                               bf16* __restrict__ bt2) {
  int bid = blockIdx.x;          // 4608 blocks
  int widx = bid / 2304;
  int lb = bid % 2304;
  const float* w = widx ? w2 : w1;
  bf16* bt = widx ? bt2 : bt1;
  float mean = wq[widx * 4], lo = wq[widx * 4 + 1], hi = wq[widx * 4 + 2];
  int e = lb * 256 + threadIdx.x;
  float tv = w[e] - mean;
  float q = tv < lo ? -1.f : (tv > hi ? 1.f : 0.f);
  int o = e / 2304;
  int r = e % 2304;
  int c = r / 9;
  int s = r % 9;
  if (s == 4) q *= 2.f;          // fold the "extra" center einsum in
  bt[(size_t)o * 2304 + s * 256 + c] = (bf16)q;
}

// ---------------- NCHW fp32 -> padded NHWC bf16 ----------------
__global__ __launch_bounds__(256) void pad_convert(const float* __restrict__ x,
                                                   bf16* __restrict__ xpad) {
  int bid = blockIdx.x;
  int cchunk = bid & 3;
  int hp = (bid >> 2) % HP;
  int n = (bid >> 2) / HP;
  int t = threadIdx.x;
  bf16* orow = xpad + (size_t)(n * HP + hp) * HP * CCH;
  if (hp == 0 || hp == HP - 1) {
    for (int j = t; j < HP * 64; j += 256)
      orow[(size_t)(j >> 6) * CCH + cchunk * 64 + (j & 63)] = (bf16)0.f;
    return;
  }
  int h = hp - 1;
  __shared__ float tile[HH * 65];
  const float* xb = x + ((size_t)n * CCH + cchunk * 64) * (HH * HH) + h * HH;
  for (int j = t; j < 64 * 64; j += 256) {
    int w = j & 63, cc = j >> 6;
    if (w < HH) tile[w * 65 + cc] = xb[(size_t)cc * (HH * HH) + w];
  }
  __syncthreads();
  for (int j = t; j < HP * 64; j += 256) {
    int wp = j >> 6, cc = j & 63;
    float v = (wp == 0 || wp == HP - 1) ? 0.f : tile[(wp - 1) * 65 + cc];
    orow[(size_t)wp * CCH + cchunk * 64 + cc] = (bf16)v;
  }
}

// ---------------- conv as implicit GEMM (bf16 MFMA) ----------------
// MODE 0: write raw NHWC fp32 + fused BN stats partials
// MODE 1: fused BN stats partials only
// MODE 2: epilogue bn2 + residual(out1pad) + relu -> NCHW fp32
template <int MODE>
__global__ __launch_bounds__(256) void conv_gemm(const bf16* __restrict__ xpad,
                                                 const bf16* __restrict__ bt,
                                                 float* __restrict__ outr,
                                                 float* __restrict__ part,
                                                 const bf16* __restrict__ v1pad,
                                                 const float* __restrict__ bnp,
                                                 float* __restrict__ outf) {
  __shared__ __align__(16) char smem[4096 + 16640];
  const int t = threadIdx.x;
  const int lane = t & 63, wv = t >> 6;
  const int bid = blockIdx.x;
  const int n = bid / HH, h = bid % HH;

  const int mA = t >> 2;
  const int gA = (t & 3) ^ ((t >> 3) & 3);
  const int gB = (t & 3) ^ ((t >> 3) & 3);
  const int oB = t >> 2;

  const bf16* xrow = xpad + (size_t)(n * HP + h) * HP * CCH;
  char* ldsA = smem;
  char* ldsB = smem + 4096;
  char* ldsA_dst = ldsA + wv * 1024;

  f32x4 acc[4][4];
#pragma unroll
  for (int i = 0; i < 4; i++)
#pragma unroll
    for (int j = 0; j < 4; j++) acc[i][j] = f32x4{0.f, 0.f, 0.f, 0.f};

  const int g = lane >> 4;
  int offA[4], offB[4];
#pragma unroll
  for (int fm = 0; fm < 4; fm++) {
    int m = fm * 16 + (lane & 15);
    offA[fm] = m * 64 + ((g ^ ((m >> 1) & 3)) * 16);
  }
#pragma unroll
  for (int fn = 0; fn < 4; fn++) {
    int o = wv * 64 + fn * 16 + (lane & 15);
    offB[fn] = o * 64 + ((g ^ ((o >> 1) & 3)) * 16);
  }

  for (int s = 0; s < 9; s++) {
    const int dh = s / 3, dw = s % 3;
    const bf16* aptr = xrow + (size_t)(dh * HP + dw + mA) * CCH + gA * 8;
    const bf16* bptr = bt + (size_t)oB * 2304 + s * 256 + gB * 8;
    for (int c0 = 0; c0 < 256; c0 += 32) {
      gload16(aptr + c0, ldsA_dst);
#pragma unroll
      for (int i = 0; i < 4; i++)
        gload16(bptr + (size_t)i * 64 * 2304 + c0, ldsB + i * 4096 + wv * 1024);
      __syncthreads();
      bf16x8 af[4], bfr[4];
#pragma unroll
      for (int fm = 0; fm < 4; fm++) af[fm] = *(const bf16x8*)(ldsA + offA[fm]);
#pragma unroll
      for (int fn = 0; fn < 4; fn++) bfr[fn] = *(const bf16x8*)(ldsB + offB[fn]);
#pragma unroll
      for (int fm = 0; fm < 4; fm++)
#pragma unroll
        for (int fn = 0; fn < 4; fn++)
          acc[fm][fn] = __builtin_amdgcn_mfma_f32_16x16x32_bf16(af[fm], bfr[fn], acc[fm][fn], 0, 0, 0);
      __syncthreads();
    }
  }

  if (MODE == 0 || MODE == 1) {
    // stats partials (valid rows m < HH only), deterministic
    float so[4] = {0.f, 0.f, 0.f, 0.f}, qo[4] = {0.f, 0.f, 0.f, 0.f};
    float* obase = (MODE == 0) ? outr + (size_t)(n * HH + h) * HH * CCH : nullptr;
#pragma unroll
    for (int fm = 0; fm < 4; fm++) {
#pragma unroll
      for (int r = 0; r < 4; r++) {
        int m = fm * 16 + (lane >> 4) * 4 + r;
        if (m < HH) {
#pragma unroll
          for (int fn = 0; fn < 4; fn++) {
            float v = acc[fm][fn][r];
            so[fn] += v;
            qo[fn] += v * v;
            if (MODE == 0) {
              int o = wv * 64 + fn * 16 + (lane & 15);
              obase[(size_t)m * CCH + o] = v;
            }
          }
        }
      }
    }
#pragma unroll
    for (int fn = 0; fn < 4; fn++) {
      so[fn] += __shfl_xor(so[fn], 16);
      so[fn] += __shfl_xor(so[fn], 32);
      qo[fn] += __shfl_xor(qo[fn], 16);
      qo[fn] += __shfl_xor(qo[fn], 32);
    }
    if ((lane >> 4) == 0) {
#pragma unroll
      for (int fn = 0; fn < 4; fn++) {
        int o = wv * 64 + fn * 16 + lane;
        part[((size_t)bid * CCH + o) * 2 + 0] = so[fn];
        part[((size_t)bid * CCH + o) * 2 + 1] = qo[fn];
      }
    }
  } else {
    // MODE 2: bn2 + residual + relu, LDS transpose to NCHW
    float sc[4], bi[4];
#pragma unroll
    for (int fn = 0; fn < 4; fn++) {
      int o = wv * 64 + fn * 16 + (lane & 15);
      sc[fn] = bnp[o * 2];
      bi[fn] = bnp[o * 2 + 1];
    }
    const bf16* v1base = v1pad + ((size_t)(n * HP + h + 1) * HP + 1) * CCH;
    float* tile = (float*)smem;   // [64][65] floats = 16640 B
    for (int oc = 0; oc < 4; oc++) {
      __syncthreads();
      if (wv == oc) {
#pragma unroll
        for (int fm = 0; fm < 4; fm++) {
#pragma unroll
          for (int r = 0; r < 4; r++) {
            int m = fm * 16 + (lane >> 4) * 4 + r;
            if (m < HH) {
#pragma unroll
              for (int fn = 0; fn < 4; fn++) {
                int o_loc = fn * 16 + (lane & 15);
                int o = oc * 64 + o_loc;
                float v2 = acc[fm][fn][r] * sc[fn] + bi[fn];
                float v1 = (float)v1base[(size_t)m * CCH + o];
                float v = v1 + v2;
                tile[m * 65 + o_loc] = v > 0.f ? v : 0.f;
              }
            }
          }
        }
      }
      __syncthreads();
      for (int j = t; j < 64 * 64; j += 256) {
        int m = j & 63, oo = j >> 6;
        if (m < HH)
          outf[(((size_t)n * CCH + oc * 64 + oo) * HH + h) * HH + m] = tile[m * 65 + oo];
      }
    }
  }
}

// ---------------- BN reduce: 896 partials -> affine params ----------------
__global__ __launch_bounds__(256) void bn_reduce(const float* __restrict__ part,
                                                 const float* __restrict__ gamma,
                                                 const float* __restrict__ beta,
                                                 float* __restrict__ params) {
  int t = threadIdx.x;   // channel
  float s = 0.f, q = 0.f;
  for (int b = 0; b < NBLK; b++) {
    s += part[((size_t)b * CCH + t) * 2 + 0];
    q += part[((size_t)b * CCH + t) * 2 + 1];
  }
  const float inv = 1.f / (float)NPOSV;
  float mean = s * inv;
  float var = q * inv - mean * mean;
  float sc = gamma[t] / sqrtf(var + 1e-5f);
  params[t * 2 + 0] = sc;
  params[t * 2 + 1] = beta[t] - mean * sc;
}

// ---------------- BN apply + relu + pad -> bf16 NHWC ----------------
__global__ __launch_bounds__(256) void bn_apply_pad(const float* __restrict__ raw,
                                                    const float* __restrict__ params,
                                                    bf16* __restrict__ xpad) {
  int bid = blockIdx.x;
  int hp = bid % HP;
  int n = bid / HP;
  int t = threadIdx.x;
  bf16* orow = xpad + (size_t)(n * HP + hp) * HP * CCH;
  if (hp == 0 || hp == HP - 1) {
    for (int j = t; j < HP * CCH; j += 256) orow[j] = (bf16)0.f;
    return;
  }
  float sc = params[t * 2], bi = params[t * 2 + 1];
  const float* irow = raw + (size_t)(n * HH + (hp - 1)) * HH * CCH;
  for (int j = t; j < HP * CCH; j += 256) {
    int wp = j >> 8;   // j & 255 == t
    float v = 0.f;
    if (wp >= 1 && wp <= HH) {
      v = irow[(size_t)(wp - 1) * CCH + t] * sc + bi;
      v = v > 0.f ? v : 0.f;
    }
    orow[j] = (bf16)v;
  }
}

// ---------------- launch ----------------

extern "C" void kernel_launch(void* const* d_in, const int* in_sizes, int n_in,
                              void* d_out, int out_size, void* d_ws, size_t ws_size,
                              hipStream_t stream) {
  const float* x  = (const float*)d_in[0];
  const float* w1 = (const float*)d_in[1];
  const float* w2 = (const float*)d_in[2];
  const float* g1 = (const float*)d_in[3];
  const float* b1 = (const float*)d_in[4];
  const float* g2 = (const float*)d_in[5];
  const float* b2 = (const float*)d_in[6];
  float* out = (float*)d_out;
  char* ws = (char*)d_ws;

  // workspace layout (total ~30.3 MB)
  constexpr size_t O_BT1  = 0;                                  // 1,179,648
  constexpr size_t O_BT2  = O_BT1 + 1179648;                    // 1,179,648
  constexpr size_t O_XPAD = O_BT2 + 1179648;                    // 27,557,888 (reused as out1pad)
  constexpr size_t O_PART = O_XPAD + (size_t)NIMG * HP * HP * CCH * 2;  // 1,835,008
  constexpr size_t O_PSUM = O_PART + (size_t)NBLK * CCH * 2 * 4;
  constexpr size_t O_PMN  = O_PSUM + 2048;
  constexpr size_t O_PMX  = O_PMN + 1024;
  constexpr size_t O_WQ   = O_PMX + 1024;
  constexpr size_t O_BNP1 = O_WQ + 256;
  constexpr size_t O_BNP2 = O_BNP1 + 2048;

  bf16* bt1 = (bf16*)(ws + O_BT1);
  bf16* bt2 = (bf16*)(ws + O_BT2);
  bf16* xpad = (bf16*)(ws + O_XPAD);
  bf16* out1pad = (bf16*)(ws + O_XPAD);   // reuses xpad space after conv1
  float* part = (float*)(ws + O_PART);
  double* psum = (double*)(ws + O_PSUM);
  float* pmn = (float*)(ws + O_PMN);
  float* pmx = (float*)(ws + O_PMX);
  float* wq = (float*)(ws + O_WQ);
  float* bnp1 = (float*)(ws + O_BNP1);
  float* bnp2 = (float*)(ws + O_BNP2);
  float* out1raw = out;   // d_out reused as conv1 raw scratch (dead before final write)

  w_partial<<<256, 256, 0, stream>>>(w1, w2, psum, pmn, pmx);
  w_finalize<<<1, 64, 0, stream>>>(psum, pmn, pmx, wq);
  w_quant<<<4608, 256, 0, stream>>>(w1, w2, wq, bt1, bt2);
  pad_convert<<<NIMG * HP * 4, 256, 0, stream>>>(x, xpad);
  conv_gemm<0><<<NBLK, 256, 0, stream>>>(xpad, bt1, out1raw, part, nullptr, nullptr, nullptr);
  bn_reduce<<<1, 256, 0, stream>>>(part, g1, b1, bnp1);
  bn_apply_pad<<<NIMG * HP, 256, 0, stream>>>(out1raw, bnp1, out1pad);
  conv_gemm<1><<<NBLK, 256, 0, stream>>>(out1pad, bt2, nullptr, part, nullptr, nullptr, nullptr);
  bn_reduce<<<1, 256, 0, stream>>>(part, g2, b2, bnp2);
  conv_gemm<2><<<NBLK, 256, 0, stream>>>(out1pad, bt2, nullptr, nullptr, out1pad, bnp2, out);
}

// Round 3
// 300.927 us; speedup vs baseline: 1.9641x; 1.9641x over previous
//
#include <hip/hip_runtime.h>

typedef __bf16 bf16;
typedef __bf16 bf16x8 __attribute__((ext_vector_type(8)));
typedef float f32x4 __attribute__((ext_vector_type(4)));

#define NIMG 16
#define CCH 256
#define HH 56
#define HP 58
#define NBLK2 (NIMG * 28)        // 448 conv blocks (2 rows each)
#define NPART 896                // 448 blocks * 2 row-halves
#define NPOSV (NIMG * HH * HH)   // 50176 valid positions
#define WELEMS 589824            // 256*256*3*3

typedef const __attribute__((address_space(1))) void* gas1_t;
typedef __attribute__((address_space(3))) void* las3_t;

__device__ __forceinline__ void gload16(const void* g, void* l) {
  __builtin_amdgcn_global_load_lds((gas1_t)g, (las3_t)l, 16, 0, 0);
}

// ---------------- weight quantization ----------------

__global__ __launch_bounds__(256) void w_partial(const float* __restrict__ w1,
                                                 const float* __restrict__ w2,
                                                 double* __restrict__ psum,
                                                 float* __restrict__ pmn,
                                                 float* __restrict__ pmx) {
  int b = blockIdx.x;            // 256 blocks: 128 per weight
  int lb = b & 127;
  const float* w = (b >> 7) ? w2 : w1;
  int t = threadIdx.x;
  double s = 0.0;
  float mn = 3.4028235e38f, mx = -3.4028235e38f;
  for (int i = lb * 4608 + t; i < (lb + 1) * 4608; i += 256) {
    float v = w[i];
    s += (double)v;
    mn = fminf(mn, v);
    mx = fmaxf(mx, v);
  }
  __shared__ double sd[256];
  __shared__ float smn[256], smx[256];
  sd[t] = s; smn[t] = mn; smx[t] = mx;
  __syncthreads();
  for (int st = 128; st > 0; st >>= 1) {
    if (t < st) {
      sd[t] += sd[t + st];
      smn[t] = fminf(smn[t], smn[t + st]);
      smx[t] = fmaxf(smx[t], smx[t + st]);
    }
    __syncthreads();
  }
  if (t == 0) { psum[b] = sd[0]; pmn[b] = smn[0]; pmx[b] = smx[0]; }
}

__global__ void w_finalize(const double* __restrict__ psum,
                           const float* __restrict__ pmn,
                           const float* __restrict__ pmx,
                           float* __restrict__ wq) {
  int t = threadIdx.x;
  if (t < 2) {
    double s = 0.0;
    float mn = 3.4028235e38f, mx = -3.4028235e38f;
    for (int b = t * 128; b < (t + 1) * 128; b++) {
      s += psum[b];
      mn = fminf(mn, pmn[b]);
      mx = fmaxf(mx, pmx[b]);
    }
    float mean = (float)(s / (double)WELEMS);
    float tmn = mn - mean, tmx = mx - mean;
    float d = (tmx - tmn) / 3.0f;
    wq[t * 4 + 0] = mean;
    wq[t * 4 + 1] = tmn + d;   // lo
    wq[t * 4 + 2] = tmx - d;   // hi
  }
}

// produce B^T layout: bt[o][k], k = (kh*3+kw)*256 + c, center tap doubled
__global__ __launch_bounds__(256) void w_quant(const float* __restrict__ w1,
                                               const float* __restrict__ w2,
                                               const float* __restrict__ wq,
                                               bf16* __restrict__ bt1,
                                               bf16* __restrict__ bt2) {
  int bid = blockIdx.x;          // 4608 blocks
  int widx = bid / 2304;
  int lb = bid % 2304;
  const float* w = widx ? w2 : w1;
  bf16* bt = widx ? bt2 : bt1;
  float mean = wq[widx * 4], lo = wq[widx * 4 + 1], hi = wq[widx * 4 + 2];
  int e = lb * 256 + threadIdx.x;
  float tv = w[e] - mean;
  float q = tv < lo ? -1.f : (tv > hi ? 1.f : 0.f);
  int o = e / 2304;
  int r = e % 2304;
  int c = r / 9;
  int s = r % 9;
  if (s == 4) q *= 2.f;          // fold the "extra" center einsum in
  bt[(size_t)o * 2304 + s * 256 + c] = (bf16)q;
}

// ---------------- NCHW fp32 -> padded NHWC bf16 ----------------
__global__ __launch_bounds__(256) void pad_convert(const float* __restrict__ x,
                                                   bf16* __restrict__ xpad) {
  int bid = blockIdx.x;
  int cchunk = bid & 3;
  int hp = (bid >> 2) % HP;
  int n = (bid >> 2) / HP;
  int t = threadIdx.x;
  bf16* orow = xpad + (size_t)(n * HP + hp) * HP * CCH;
  if (hp == 0 || hp == HP - 1) {
    for (int j = t; j < HP * 64; j += 256)
      orow[(size_t)(j >> 6) * CCH + cchunk * 64 + (j & 63)] = (bf16)0.f;
    return;
  }
  int h = hp - 1;
  __shared__ float tile[HH * 65];
  const float* xb = x + ((size_t)n * CCH + cchunk * 64) * (HH * HH) + h * HH;
  for (int j = t; j < 64 * 64; j += 256) {
    int w = j & 63, cc = j >> 6;
    if (w < HH) tile[w * 65 + cc] = xb[(size_t)cc * (HH * HH) + w];
  }
  __syncthreads();
  for (int j = t; j < HP * 64; j += 256) {
    int wp = j >> 6, cc = j & 63;
    float v = (wp == 0 || wp == HP - 1) ? 0.f : tile[(wp - 1) * 65 + cc];
    orow[(size_t)wp * CCH + cchunk * 64 + cc] = (bf16)v;
  }
}

// ---------------- staging helpers ----------------
// A-LDS: entry (r,p,s8) at r*8192 + p*128 + s8*16 ; holds channel group s8^(p&7)
__device__ __forceinline__ void stage_A(const bf16* __restrict__ xpad, int n, int h0,
                                        int cc, char* smem, int abase, int wv, int lane) {
  int p = wv * 8 + (lane >> 3);
  int g = (lane & 7) ^ (lane >> 3);     // s8 ^ (p&7)
#pragma unroll
  for (int r = 0; r < 4; ++r) {
    const bf16* src = xpad + ((size_t)(n * HP + h0 + r) * HP + p) * CCH + cc * 64 + g * 8;
    gload16(src, smem + abase + r * 8192 + wv * 1024);
  }
}

// B-LDS: entry (o,s8) at o*128 + s8*16 ; holds channel group s8^(o&7)
__device__ __forceinline__ void stage_B(const bf16* __restrict__ bt, int s, int cc,
                                        char* smem, int bbase, int wv, int lane) {
  int g = (lane & 7) ^ (lane >> 3);     // s8 ^ (o&7)
#pragma unroll
  for (int j = 0; j < 4; ++j) {
    int o = j * 64 + wv * 8 + (lane >> 3);
    const bf16* src = bt + (size_t)o * 2304 + s * 256 + cc * 64 + g * 8;
    gload16(src, smem + bbase + j * 8192 + wv * 1024);
  }
}

// ---------------- conv as implicit GEMM, M=128 (2 rows), N=256, 8 waves ----------------
// MODE 0: raw NHWC fp32 + fused BN stats partials
// MODE 1: fused BN stats partials only
// MODE 2: bn2 + residual(out1pad) + relu -> NCHW fp32
template <int MODE>
__global__ __launch_bounds__(512, 2) void conv_gemm(const bf16* __restrict__ xpad,
                                                    const bf16* __restrict__ bt,
                                                    float* __restrict__ outr,
                                                    float* __restrict__ part,
                                                    const bf16* __restrict__ v1pad,
                                                    const float* __restrict__ bnp,
                                                    float* __restrict__ outf) {
  __shared__ __align__(16) char smem[131072];   // A0 @0, A1 @32768, B0 @65536, B1 @98304
  const int t = threadIdx.x;
  const int lane = t & 63, wv = t >> 6;
  const int wm = wv >> 2, wn = wv & 3;          // wave tile: row wm, out-chunk wn
  const int g = lane >> 4, li = lane & 15;
  const int bid = blockIdx.x;
  const int n = bid / 28, h0 = (bid % 28) * 2;

  f32x4 acc[4][4];
#pragma unroll
  for (int i = 0; i < 4; i++)
#pragma unroll
    for (int j = 0; j < 4; j++) acc[i][j] = f32x4{0.f, 0.f, 0.f, 0.f};

  // B read offsets (phase-invariant)
  int bo[4][2];
#pragma unroll
  for (int fn = 0; fn < 4; ++fn)
#pragma unroll
    for (int kk = 0; kk < 2; ++kk) {
      int o = wn * 64 + fn * 16 + li;
      bo[fn][kk] = o * 128 + (((kk * 4 + g) ^ (o & 7)) * 16);
    }

  stage_A(xpad, n, h0, 0, smem, 0, wv, lane);
  stage_B(bt, 0, 0, smem, 65536, wv, lane);
  __syncthreads();

  for (int cc = 0; cc < 4; ++cc) {
    const int abase = (cc & 1) * 32768;
#pragma unroll
    for (int s = 0; s < 9; ++s) {
      const int dh = s / 3, dw = s % 3;
      const int curB = 65536 + (((cc + s) & 1) ? 32768 : 0);
      const int nxtB = 65536 + (((cc + s + 1) & 1) ? 32768 : 0);
      // prefetch next tiles (issue-early)
      if (s < 8) stage_B(bt, s + 1, cc, smem, nxtB, wv, lane);
      else if (cc < 3) stage_B(bt, 0, cc + 1, smem, nxtB, wv, lane);
      if (s == 0 && cc < 3) stage_A(xpad, n, h0, cc + 1, smem, abase ^ 32768, wv, lane);
      __builtin_amdgcn_sched_barrier(0);   // keep prefetch issues above compute
      // LDS -> fragments
      bf16x8 af[4][2], bfr[4][2];
#pragma unroll
      for (int fm = 0; fm < 4; ++fm) {
        int p = fm * 16 + li + dw;
#pragma unroll
        for (int kk = 0; kk < 2; ++kk) {
          int off = abase + (wm + dh) * 8192 + p * 128 + (((kk * 4 + g) ^ (p & 7)) * 16);
          af[fm][kk] = *(const bf16x8*)(smem + off);
        }
      }
#pragma unroll
      for (int fn = 0; fn < 4; ++fn)
#pragma unroll
        for (int kk = 0; kk < 2; ++kk)
          bfr[fn][kk] = *(const bf16x8*)(smem + curB + bo[fn][kk]);
#pragma unroll
      for (int kk = 0; kk < 2; ++kk)
#pragma unroll
        for (int fm = 0; fm < 4; ++fm)
#pragma unroll
          for (int fn = 0; fn < 4; ++fn)
            acc[fm][fn] = __builtin_amdgcn_mfma_f32_16x16x32_bf16(af[fm][kk], bfr[fn][kk],
                                                                  acc[fm][fn], 0, 0, 0);
      __syncthreads();
    }
  }

  if (MODE == 0 || MODE == 1) {
    float so[4] = {0.f, 0.f, 0.f, 0.f}, qo[4] = {0.f, 0.f, 0.f, 0.f};
    float* obase = (MODE == 0) ? outr + (size_t)(n * HH + h0 + wm) * HH * CCH : nullptr;
#pragma unroll
    for (int fm = 0; fm < 4; ++fm) {
#pragma unroll
      for (int r = 0; r < 4; ++r) {
        int m = fm * 16 + g * 4 + r;
        if (m < HH) {
#pragma unroll
          for (int fn = 0; fn < 4; ++fn) {
            float v = acc[fm][fn][r];
            so[fn] += v;
            qo[fn] += v * v;
            if (MODE == 0) obase[(size_t)m * CCH + wn * 64 + fn * 16 + li] = v;
          }
        }
      }
    }
#pragma unroll
    for (int fn = 0; fn < 4; ++fn) {
      so[fn] += __shfl_xor(so[fn], 16);
      so[fn] += __shfl_xor(so[fn], 32);
      qo[fn] += __shfl_xor(qo[fn], 16);
      qo[fn] += __shfl_xor(qo[fn], 32);
    }
    if (g == 0) {
#pragma unroll
      for (int fn = 0; fn < 4; ++fn) {
        int o = wn * 64 + fn * 16 + lane;
        part[((size_t)(bid * 2 + wm) * CCH + o) * 2 + 0] = so[fn];
        part[((size_t)(bid * 2 + wm) * CCH + o) * 2 + 1] = qo[fn];
      }
    }
  } else {
    // MODE 2: bn2 + residual + relu, LDS transpose to NCHW
    float sc[4], bi[4];
#pragma unroll
    for (int fn = 0; fn < 4; ++fn) {
      int o = wn * 64 + fn * 16 + li;
      sc[fn] = bnp[o * 2];
      bi[fn] = bnp[o * 2 + 1];
    }
    const bf16* v1base = v1pad + ((size_t)(n * HP + h0 + wm + 1) * HP + 1) * CCH;
    float* tile = (float*)smem;   // 64*65 floats
    for (int oc = 0; oc < 4; ++oc) {
      for (int rr = 0; rr < 2; ++rr) {
        __syncthreads();
        if (wn == oc && wm == rr) {
#pragma unroll
          for (int fm = 0; fm < 4; ++fm) {
#pragma unroll
            for (int r = 0; r < 4; ++r) {
              int m = fm * 16 + g * 4 + r;
              if (m < HH) {
#pragma unroll
                for (int fn = 0; fn < 4; ++fn) {
                  int o_loc = fn * 16 + li;
                  float v2 = acc[fm][fn][r] * sc[fn] + bi[fn];
                  float v1 = (float)v1base[(size_t)m * CCH + oc * 64 + o_loc];
                  float v = v1 + v2;
                  tile[m * 65 + o_loc] = v > 0.f ? v : 0.f;
                }
              }
            }
          }
        }
        __syncthreads();
        for (int j = t; j < 64 * 64; j += 512) {
          int w = j & 63, oo = j >> 6;
          if (w < HH)
            outf[(((size_t)n * CCH + oc * 64 + oo) * HH + h0 + rr) * HH + w] = tile[w * 65 + oo];
        }
      }
    }
  }
}

// ---------------- BN reduce: 896 partial rows -> affine params (2-stage) ----------------
__global__ __launch_bounds__(256) void bn_reduce1(const float* __restrict__ part,
                                                  float* __restrict__ part2) {
  int t = threadIdx.x, b = blockIdx.x;   // 32 blocks, 28 rows each
  float s = 0.f, q = 0.f;
  for (int r = b * 28; r < (b + 1) * 28; r++) {
    s += part[((size_t)r * CCH + t) * 2 + 0];
    q += part[((size_t)r * CCH + t) * 2 + 1];
  }
  part2[((size_t)b * CCH + t) * 2 + 0] = s;
  part2[((size_t)b * CCH + t) * 2 + 1] = q;
}

__global__ __launch_bounds__(256) void bn_reduce2(const float* __restrict__ part2,
                                                  const float* __restrict__ gamma,
                                                  const float* __restrict__ beta,
                                                  float* __restrict__ params) {
  int t = threadIdx.x;   // channel
  float s = 0.f, q = 0.f;
  for (int b = 0; b < 32; b++) {
    s += part2[((size_t)b * CCH + t) * 2 + 0];
    q += part2[((size_t)b * CCH + t) * 2 + 1];
  }
  const float inv = 1.f / (float)NPOSV;
  float mean = s * inv;
  float var = q * inv - mean * mean;
  float sc = gamma[t] / sqrtf(var + 1e-5f);
  params[t * 2 + 0] = sc;
  params[t * 2 + 1] = beta[t] - mean * sc;
}

// ---------------- BN apply + relu + pad -> bf16 NHWC ----------------
__global__ __launch_bounds__(256) void bn_apply_pad(const float* __restrict__ raw,
                                                    const float* __restrict__ params,
                                                    bf16* __restrict__ xpad) {
  int bid = blockIdx.x;
  int hp = bid % HP;
  int n = bid / HP;
  int t = threadIdx.x;
  bf16* orow = xpad + (size_t)(n * HP + hp) * HP * CCH;
  if (hp == 0 || hp == HP - 1) {
    for (int j = t; j < HP * CCH; j += 256) orow[j] = (bf16)0.f;
    return;
  }
  float sc = params[t * 2], bi = params[t * 2 + 1];
  const float* irow = raw + (size_t)(n * HH + (hp - 1)) * HH * CCH;
  for (int j = t; j < HP * CCH; j += 256) {
    int wp = j >> 8;   // j & 255 == t
    float v = 0.f;
    if (wp >= 1 && wp <= HH) {
      v = irow[(size_t)(wp - 1) * CCH + t] * sc + bi;
      v = v > 0.f ? v : 0.f;
    }
    orow[j] = (bf16)v;
  }
}

// ---------------- launch ----------------

extern "C" void kernel_launch(void* const* d_in, const int* in_sizes, int n_in,
                              void* d_out, int out_size, void* d_ws, size_t ws_size,
                              hipStream_t stream) {
  const float* x  = (const float*)d_in[0];
  const float* w1 = (const float*)d_in[1];
  const float* w2 = (const float*)d_in[2];
  const float* g1 = (const float*)d_in[3];
  const float* b1 = (const float*)d_in[4];
  const float* g2 = (const float*)d_in[5];
  const float* b2 = (const float*)d_in[6];
  float* out = (float*)d_out;
  char* ws = (char*)d_ws;

  constexpr size_t O_BT1  = 0;                                   // 1,179,648
  constexpr size_t O_BT2  = O_BT1 + 1179648;
  constexpr size_t O_XPAD = O_BT2 + 1179648;                     // 27,557,888 (+64K tail pad)
  constexpr size_t O_PART = O_XPAD + (size_t)NIMG * HP * HP * CCH * 2 + 65536;
  constexpr size_t O_PSUM = O_PART + (size_t)NPART * CCH * 2 * 4; // part: 1,835,008
  constexpr size_t O_PMN  = O_PSUM + 2048;
  constexpr size_t O_PMX  = O_PMN + 1024;
  constexpr size_t O_WQ   = O_PMX + 1024;
  constexpr size_t O_BNP1 = O_WQ + 256;
  constexpr size_t O_BNP2 = O_BNP1 + 2048;
  constexpr size_t O_PART2 = O_BNP2 + 2048;                      // 65,536

  bf16* bt1 = (bf16*)(ws + O_BT1);
  bf16* bt2 = (bf16*)(ws + O_BT2);
  bf16* xpad = (bf16*)(ws + O_XPAD);
  bf16* out1pad = (bf16*)(ws + O_XPAD);   // reuses xpad space after conv1
  float* part = (float*)(ws + O_PART);
  double* psum = (double*)(ws + O_PSUM);
  float* pmn = (float*)(ws + O_PMN);
  float* pmx = (float*)(ws + O_PMX);
  float* wq = (float*)(ws + O_WQ);
  float* bnp1 = (float*)(ws + O_BNP1);
  float* bnp2 = (float*)(ws + O_BNP2);
  float* part2 = (float*)(ws + O_PART2);
  float* out1raw = out;   // d_out reused as conv1 raw scratch (dead before final write)

  w_partial<<<256, 256, 0, stream>>>(w1, w2, psum, pmn, pmx);
  w_finalize<<<1, 64, 0, stream>>>(psum, pmn, pmx, wq);
  w_quant<<<4608, 256, 0, stream>>>(w1, w2, wq, bt1, bt2);
  pad_convert<<<NIMG * HP * 4, 256, 0, stream>>>(x, xpad);
  conv_gemm<0><<<NBLK2, 512, 0, stream>>>(xpad, bt1, out1raw, part, nullptr, nullptr, nullptr);
  bn_reduce1<<<32, 256, 0, stream>>>(part, part2);
  bn_reduce2<<<1, 256, 0, stream>>>(part2, g1, b1, bnp1);
  bn_apply_pad<<<NIMG * HP, 256, 0, stream>>>(out1raw, bnp1, out1pad);
  conv_gemm<1><<<NBLK2, 512, 0, stream>>>(out1pad, bt2, nullptr, part, nullptr, nullptr, nullptr);
  bn_reduce1<<<32, 256, 0, stream>>>(part, part2);
  bn_reduce2<<<1, 256, 0, stream>>>(part2, g2, b2, bnp2);
  conv_gemm<2><<<NBLK2, 512, 0, stream>>>(out1pad, bt2, nullptr, nullptr, out1pad, bnp2, out);
}